// Round 12
// baseline (154.628 us; speedup 1.0000x reference)
//
#include <hip/hip_runtime.h>
#include <hip/hip_bf16.h>
#include <stdint.h>

#define BB 2
#define SS 2048
#define DDIM 1024
#define HH 16
#define DEPTH 64
#define MROWS (BB*SS)   // 4096

typedef short bf16x8 __attribute__((ext_vector_type(8)));
typedef float f32x4 __attribute__((ext_vector_type(4)));

__device__ inline ushort f2bf(float f) {
  union { float f; unsigned u; } v; v.f = f;
  unsigned r = v.u + 0x7fffu + ((v.u >> 16) & 1u);
  return (ushort)(r >> 16);
}

// HW packed f32x2 -> bf16x2 (RTNE), low = a, high = b  [m214 T12]
__device__ inline uint pkbf(float a, float b) {
  uint r;
  asm("v_cvt_pk_bf16_f32 %0, %1, %2" : "=v"(r) : "v"(a), "v"(b));
  return r;
}

__device__ inline void gload_lds16(const void* g, void* l) {
  __builtin_amdgcn_global_load_lds(
      (const __attribute__((address_space(1))) unsigned*)g,
      (__attribute__((address_space(3))) unsigned*)l,
      16, 0, 0);
}

#define SBAR()  __builtin_amdgcn_sched_barrier(0)

// ---------------- weight transpose + convert: T[n][k] = W[k][n] ----------------
__global__ void wprep_kernel(const float* __restrict__ W0, const float* __restrict__ W1,
                             const float* __restrict__ W2, const float* __restrict__ W3,
                             ushort* __restrict__ T0, ushort* __restrict__ T1,
                             ushort* __restrict__ T2, ushort* __restrict__ T3) {
  __shared__ float tile[32][33];
  int z = blockIdx.x >> 10;
  int rr = blockIdx.x & 1023;
  const float* W = (z == 0) ? W0 : (z == 1) ? W1 : (z == 2) ? W2 : W3;
  ushort* T = (z == 0) ? T0 : (z == 1) ? T1 : (z == 2) ? T2 : T3;
  int tx = threadIdx.x & 31, ty = threadIdx.x >> 5;   // 32 x 8
  int n0 = (rr & 31) * 32, k0 = (rr >> 5) * 32;
#pragma unroll
  for (int i = 0; i < 4; i++)
    tile[ty + i * 8][tx] = W[(size_t)(k0 + ty + i * 8) * DDIM + n0 + tx];
  __syncthreads();
#pragma unroll
  for (int i = 0; i < 4; i++)
    T[(size_t)(n0 + ty + i * 8) * DDIM + k0 + tx] = f2bf(tile[tx][ty + i * 8]);
}

// ---------------- fused Q/K/V projection GEMM, BK=64, counted-vmcnt pipeline -----
// T4: raw s_barrier + counted s_waitcnt; loads stay in flight across barriers.
// Invariant at each step top: 8 A-loads (tile t+1) outstanding.
__global__ __launch_bounds__(256, 3) void qkv_gemm_kernel(
    const float* __restrict__ Aq, const float* __restrict__ Ak, const float* __restrict__ Av,
    const ushort* __restrict__ Wqt, const ushort* __restrict__ Wkt, const ushort* __restrict__ Wvt,
    const float* __restrict__ bqp, const float* __restrict__ bkp, const float* __restrict__ bvp,
    ushort* __restrict__ Qh, ushort* __restrict__ Kh, ushort* __restrict__ Vtg) {
  const int id = blockIdx.x;
  const int xcd = id & 7;
  const int rest = id >> 3;          // 0..95
  const int xblk = rest & 7;         // n-block 0..7
  const int slot = rest >> 3;        // 0..11
  const int g = xcd * 12 + slot;     // 0..95
  const int yblk = g & 31;           // m-panel 0..31
  const int z = g >> 5;              // tensor 0..2

  const float*  Ap = (z == 0) ? Aq  : (z == 1) ? Ak  : Av;
  const ushort* Bt = (z == 0) ? Wqt : (z == 1) ? Wkt : Wvt;
  const float* bias = (z == 0) ? bqp : (z == 1) ? bkp : bvp;

  __shared__ __align__(16) ushort As[128 * 64];        // 16 KB
  __shared__ __align__(16) ushort Bs[2][128 * 64];     // 32 KB
  const int tid = threadIdx.x;
  const int w = tid >> 6, lane = tid & 63;
  const int m0 = yblk * 128, n0 = xblk * 128;
  const int wr = (w >> 1) * 64, wc = (w & 1) * 64;
  const int l4 = lane >> 4, l15 = lane & 15;
  const int row16 = tid >> 4;          // 0..15
  const int col4 = (tid & 15) * 4;     // fp32/bf16 col within 64
  const int srow8 = w * 8 + (lane >> 3);
  const int scol8 = (lane & 7) * 8;

  f32x4 zero = {0.f, 0.f, 0.f, 0.f};
  f32x4 acc[4][4];
#pragma unroll
  for (int i = 0; i < 4; i++)
#pragma unroll
    for (int j = 0; j < 4; j++) acc[i][j] = zero;

  float4 aregA[8], aregB[8];

#define ISSUE_A(T, AR) do {                                                     \
  _Pragma("unroll")                                                             \
  for (int j = 0; j < 8; ++j)                                                   \
    AR[j] = *(const float4*)&Ap[(size_t)(m0 + j * 16 + row16) * DDIM + (T) * 64 + col4]; \
  SBAR();                                                                       \
} while (0)

#define ISSUE_B(T, S) do {                                                      \
  _Pragma("unroll")                                                             \
  for (int it = 0; it < 4; ++it)                                                \
    gload_lds16(Bt + (size_t)(n0 + it * 32 + srow8) * DDIM + (T) * 64 + scol8,  \
                &Bs[S][(it * 32 + w * 8) * 64]);                                \
  SBAR();                                                                       \
} while (0)

#define WRITE_A(AR) do {                                                        \
  _Pragma("unroll")                                                             \
  for (int j = 0; j < 8; ++j) {                                                 \
    uint2 pk;                                                                   \
    pk.x = pkbf(AR[j].x, AR[j].y);                                              \
    pk.y = pkbf(AR[j].z, AR[j].w);                                              \
    *(uint2*)&As[(j * 16 + row16) * 64 + col4] = pk;                            \
  }                                                                             \
} while (0)

#define MFMA_T(S) do {                                                          \
  _Pragma("unroll")                                                             \
  for (int kk = 0; kk < 2; ++kk) {                                              \
    bf16x8 af[4], bfr[4];                                                       \
    _Pragma("unroll")                                                           \
    for (int m = 0; m < 4; m++)                                                 \
      af[m] = *(const bf16x8*)&As[(wr + m * 16 + l15) * 64 + kk * 32 + l4 * 8]; \
    _Pragma("unroll")                                                           \
    for (int n = 0; n < 4; n++)                                                 \
      bfr[n] = *(const bf16x8*)&Bs[S][(wc + n * 16 + l15) * 64 + kk * 32 + l4 * 8]; \
    _Pragma("unroll")                                                           \
    for (int m = 0; m < 4; m++)                                                 \
      _Pragma("unroll")                                                         \
      for (int n = 0; n < 4; n++)                                               \
        acc[m][n] = __builtin_amdgcn_mfma_f32_16x16x32_bf16(af[m], bfr[n], acc[m][n], 0, 0, 0); \
  }                                                                             \
} while (0)

// Steady-state step: consumes ARcur = A(t+1); fills ARnext = A(t+2).
// vmcnt(12): A(t+1) done, leaves B(t+1)4 + A(t+2)8.
// vmcnt(8):  B(t+1) landed, leaves A(t+2)8.
#define STEP(T, ARcur, ARnext) do {                                             \
  ISSUE_B((T) + 1, buf ^ 1);                                                    \
  ISSUE_A((T) + 2, ARnext);                                                     \
  MFMA_T(buf);                                                                  \
  asm volatile("s_waitcnt vmcnt(12)"); SBAR();                                  \
  asm volatile("s_waitcnt lgkmcnt(0)"); SBAR();                                 \
  __builtin_amdgcn_s_barrier(); SBAR();                                         \
  WRITE_A(ARcur);                                                               \
  asm volatile("s_waitcnt vmcnt(8) lgkmcnt(0)"); SBAR();                        \
  __builtin_amdgcn_s_barrier(); SBAR();                                         \
  buf ^= 1;                                                                     \
} while (0)

  // ---- prologue: A(0)->As, B(0)->Bs[0], A(1)->aregA in flight ----
  ISSUE_A(0, aregA);
  ISSUE_B(0, 0);
  asm volatile("s_waitcnt vmcnt(4)"); SBAR();   // A(0) done, B(0) in flight
  WRITE_A(aregA);
  ISSUE_A(1, aregA);
  asm volatile("s_waitcnt vmcnt(8) lgkmcnt(0)"); SBAR();  // B(0) landed, A(1) in flight
  __builtin_amdgcn_s_barrier(); SBAR();

  int buf = 0;
  for (int tt = 0; tt < 14; tt += 2) {
    STEP(tt,     aregA, aregB);
    STEP(tt + 1, aregB, aregA);
  }
  // ---- t = 14 (boundary: no A(16)) ----
  ISSUE_B(15, buf ^ 1);
  MFMA_T(buf);
  asm volatile("s_waitcnt vmcnt(4)"); SBAR();   // A(15) done, B(15) in flight
  asm volatile("s_waitcnt lgkmcnt(0)"); SBAR();
  __builtin_amdgcn_s_barrier(); SBAR();
  WRITE_A(aregA);                               // A(15)
  asm volatile("s_waitcnt vmcnt(0) lgkmcnt(0)"); SBAR();
  __builtin_amdgcn_s_barrier(); SBAR();
  buf ^= 1;
  // ---- t = 15 (last) ----
  MFMA_T(buf);
  asm volatile("s_waitcnt lgkmcnt(0)"); SBAR();
  __builtin_amdgcn_s_barrier(); SBAR();

#undef STEP
#undef MFMA_T
#undef WRITE_A
#undef ISSUE_B
#undef ISSUE_A

  if (z != 2) {
    ushort* outp = (z == 0) ? Qh : Kh;
    ushort* wtile = (w < 2) ? &As[w * 4096] : &Bs[0][(w - 2) * 4096];
    const int gcol0 = n0 + wc;
    const int hh = gcol0 >> 6;
    const int bb = m0 >> 11;
    const int s0g = (m0 + wr) & (SS - 1);
#pragma unroll
    for (int m = 0; m < 4; m++) {
#pragma unroll
      for (int n = 0; n < 4; n++) {
        int dloc = n * 16 + l15;
        float bv = bias[gcol0 + dloc];
#pragma unroll
        for (int r = 0; r < 4; r++) {
          int sloc = m * 16 + l4 * 4 + r;
          wtile[sloc * 64 + (dloc ^ ((sloc & 7) << 3))] = f2bf(acc[m][n][r] + bv);
        }
      }
    }
#pragma unroll
    for (int i = 0; i < 8; ++i) {
      int srow = i * 8 + (lane >> 3);
      int dch = (lane & 7) * 8;
      bf16x8 val = *(const bf16x8*)&wtile[srow * 64 + (dch ^ ((srow & 7) << 3))];
      *(bf16x8*)&outp[((size_t)(bb * HH + hh) * SS + s0g + srow) * DEPTH + dch] = val;
    }
  } else {
    ushort* wtile = (w < 2) ? &As[w * 2048] : &Bs[0][(w - 2) * 2048];
    const int gcol0 = n0 + wc;
    const int hh = gcol0 >> 6;
    const int bb = m0 >> 11;
    const int s0g = (m0 + wr) & (SS - 1);
#pragma unroll
    for (int p = 0; p < 2; ++p) {
#pragma unroll
      for (int nn = 0; nn < 2; ++nn) {
        int n = p * 2 + nn;
        int dloc = nn * 16 + l15;
        float bv = bias[gcol0 + p * 32 + dloc];
#pragma unroll
        for (int m = 0; m < 4; m++) {
#pragma unroll
          for (int rr = 0; rr < 4; rr += 2) {
            int sloc = m * 16 + l4 * 4 + rr;
            int gg = (sloc >> 3) ^ (dloc & 7);
            uint pk = pkbf(acc[m][n][rr] + bv, acc[m][n][rr + 1] + bv);
            *(uint*)&wtile[dloc * 64 + gg * 8 + (sloc & 7)] = pk;
          }
        }
      }
      __syncthreads();
#pragma unroll
      for (int i = 0; i < 4; ++i) {
        int dloc = (lane >> 3) + i * 8;
        int gg = (lane & 7) ^ (dloc & 7);
        bf16x8 val = *(const bf16x8*)&wtile[dloc * 64 + gg * 8];
        int dglob = p * 32 + dloc;
        size_t addr = ((size_t)(bb * HH + hh) * DEPTH + dglob) * SS + s0g + (lane & 7) * 8;
        *(bf16x8*)&Vtg[addr] = val;
      }
      __syncthreads();
    }
  }
}

// ---------------- output GEMM: 128x64 tile, BK=64, full dbuf, 1 barrier/iter -----
__global__ __launch_bounds__(256, 3) void out_gemm_kernel(
    const ushort* __restrict__ A, const ushort* __restrict__ Bt,
    const float* __restrict__ bias, float* __restrict__ out,
    int M, int N, int K) {
  __shared__ __align__(16) ushort As[2][128 * 64];   // 32 KB
  __shared__ __align__(16) ushort Bs[2][64 * 64];    // 16 KB
  const int id = blockIdx.x;
  const int xcd = id & 7;
  const int rest = id >> 3;          // 0..63
  const int xblk = rest & 15;        // n-block 0..15
  const int slot = rest >> 4;        // 0..3
  const int yblk = xcd * 4 + slot;   // m-panel 0..31

  const int tid = threadIdx.x;
  const int w = tid >> 6, lane = tid & 63;
  const int m0 = yblk * 128, n0 = xblk * 64;
  const int wr = (w >> 1) * 64, wc = (w & 1) * 32;
  const int l4 = lane >> 4, l15 = lane & 15;
  const int srow8 = w * 8 + (lane >> 3);
  const int scol8 = (lane & 7) * 8;

  f32x4 zero = {0.f, 0.f, 0.f, 0.f};
  f32x4 acc[4][2];
#pragma unroll
  for (int i = 0; i < 4; i++)
#pragma unroll
    for (int j = 0; j < 2; j++) acc[i][j] = zero;

#pragma unroll
  for (int it = 0; it < 4; ++it)
    gload_lds16(A + (size_t)(m0 + it * 32 + srow8) * K + scol8,
                &As[0][(it * 32 + w * 8) * 64]);
#pragma unroll
  for (int it = 0; it < 2; ++it)
    gload_lds16(Bt + (size_t)(n0 + it * 32 + srow8) * K + scol8,
                &Bs[0][(it * 32 + w * 8) * 64]);
  __syncthreads();

  int buf = 0;
  for (int t = 0; t < 16; ++t) {
    if (t + 1 < 16) {
#pragma unroll
      for (int it = 0; it < 4; ++it)
        gload_lds16(A + (size_t)(m0 + it * 32 + srow8) * K + (t + 1) * 64 + scol8,
                    &As[buf ^ 1][(it * 32 + w * 8) * 64]);
#pragma unroll
      for (int it = 0; it < 2; ++it)
        gload_lds16(Bt + (size_t)(n0 + it * 32 + srow8) * K + (t + 1) * 64 + scol8,
                    &Bs[buf ^ 1][(it * 32 + w * 8) * 64]);
    }
#pragma unroll
    for (int kk = 0; kk < 2; ++kk) {
      bf16x8 af[4], bfr[2];
#pragma unroll
      for (int m = 0; m < 4; m++)
        af[m] = *(const bf16x8*)&As[buf][(wr + m * 16 + l15) * 64 + kk * 32 + l4 * 8];
#pragma unroll
      for (int n = 0; n < 2; n++)
        bfr[n] = *(const bf16x8*)&Bs[buf][(wc + n * 16 + l15) * 64 + kk * 32 + l4 * 8];
#pragma unroll
      for (int m = 0; m < 4; m++)
#pragma unroll
        for (int n = 0; n < 2; n++)
          acc[m][n] = __builtin_amdgcn_mfma_f32_16x16x32_bf16(af[m], bfr[n], acc[m][n], 0, 0, 0);
    }
    __syncthreads();
    buf ^= 1;
  }

#pragma unroll
  for (int m = 0; m < 4; m++) {
#pragma unroll
    for (int n = 0; n < 2; n++) {
      int col = n0 + wc + n * 16 + l15;
      float bv = bias[col];
#pragma unroll
      for (int r = 0; r < 4; r++) {
        int row = m0 + wr + m * 16 + l4 * 4 + r;
        out[(size_t)row * N + col] = acc[m][n][r] + bv;
      }
    }
  }
}

// ---------------- causal flash attention: r11 (max3 + running ptrs) -------------
__global__ __launch_bounds__(256, 4) void attn_kernel(
    const ushort* __restrict__ Qh, const ushort* __restrict__ Kh,
    const ushort* __restrict__ Vt, ushort* __restrict__ ctx) {
  __shared__ __align__(16) ushort Ks[2][64 * 64];   // [kv][d], XOR-swizzled
  __shared__ __align__(16) ushort Vs[2][64 * 64];   // [d][kv], XOR-swizzled
  __shared__ __align__(16) ushort Ps[4][16 * 64];   // per-wave P, XOR-swizzled
  const int tid = threadIdx.x;
  const int w = tid >> 6, lane = tid & 63;
  const int l4 = lane >> 4, l15 = lane & 15;
  const float CE = 0.18033688f;                     // 0.125 * log2(e)

  const int xcd = blockIdx.x & 7;
  const int local = blockIdx.x >> 3;                // 0..127
  const int bh = xcd * 4 + (local & 3);
  const int chunk = 31 - (local >> 2);
  const int b = bh >> 4, h = bh & 15;
  const size_t qkbase = (size_t)bh * SS * DEPTH;
  const size_t vbase  = (size_t)bh * DEPTH * SS;

  const int srow_w = w * 8 + (lane >> 3);
  const int colb_lin = (lane & 7) * 16;
  const int swz_rd = (l15 & 7) << 3;

  const int q0 = chunk * 64 + w * 16;
  const int nt = chunk + 1;

  const int krow0 = srow_w;
  const int kcol  = (colb_lin ^ ((krow0 & 7) << 4)) >> 1;
  const ushort* kp0 = Kh + qkbase + (size_t)krow0 * DEPTH + kcol;
  const ushort* kp1 = kp0 + 32 * DEPTH;
  const ushort* vp0 = Vt + vbase + (size_t)krow0 * SS + kcol;
  const ushort* vp1 = vp0 + 32 * SS;
  const int lds0 = w * 512;
  const int lds1 = 2048 + w * 512;

  bf16x8 aq[2];
#pragma unroll
  for (int cc = 0; cc < 2; cc++)
    aq[cc] = *(const bf16x8*)&Qh[qkbase + (size_t)(q0 + l15) * DEPTH + cc * 32 + l4 * 8];

  f32x4 zero = {0.f, 0.f, 0.f, 0.f};
  f32x4 o[4];
  float m_run = -__builtin_inff(), l_run = 0.f;
#pragma unroll
  for (int d = 0; d < 4; d++) o[d] = zero;

  int buf = 0;
  gload_lds16(kp0, &Ks[0][lds0]);
  gload_lds16(vp0, &Vs[0][lds0]);
  gload_lds16(kp1, &Ks[0][lds1]);
  gload_lds16(vp1, &Vs[0][lds1]);
  kp0 += 64 * DEPTH; kp1 += 64 * DEPTH; vp0 += 64; vp1 += 64;
  __syncthreads();

  for (int t = 0; t < nt; ++t) {
    if (t + 1 < nt) {
      gload_lds16(kp0, &Ks[buf ^ 1][lds0]);
      gload_lds16(vp0, &Vs[buf ^ 1][lds0]);
      gload_lds16(kp1, &Ks[buf ^ 1][lds1]);
      gload_lds16(vp1, &Vs[buf ^ 1][lds1]);
      kp0 += 64 * DEPTH; kp1 += 64 * DEPTH; vp0 += 64; vp1 += 64;
    }

    const int kv0 = t * 64;
    f32x4 s[4];
    __builtin_amdgcn_s_setprio(1);
#pragma unroll
    for (int n = 0; n < 4; n++) {
      f32x4 zacc = zero;
      int kr = n * 16 + l15;
#pragma unroll
      for (int cc = 0; cc < 2; cc++) {
        bf16x8 bk = *(const bf16x8*)&Ks[buf][kr * 64 + ((cc * 32 + l4 * 8) ^ swz_rd)];
        zacc = __builtin_amdgcn_mfma_f32_16x16x32_bf16(bk, aq[cc], zacc, 0, 0, 0);
      }
      s[n] = zacc;
    }
    __builtin_amdgcn_s_setprio(0);

    const int qg = q0 + l15;
    if (t == nt - 1) {
#pragma unroll
      for (int n = 0; n < 4; n++) {
        int kb = kv0 + n * 16 + l4 * 4;
#pragma unroll
        for (int r = 0; r < 4; r++)
          if (kb + r > qg) s[n][r] = -1e9f;
      }
    }

    float mx = fmaxf(fmaxf(s[0][0], s[0][1]), s[0][2]);
    mx = fmaxf(fmaxf(mx, s[0][3]), s[1][0]);
    mx = fmaxf(fmaxf(mx, s[1][1]), s[1][2]);
    mx = fmaxf(fmaxf(mx, s[1][3]), s[2][0]);
    mx = fmaxf(fmaxf(mx, s[2][1]), s[2][2]);
    mx = fmaxf(fmaxf(mx, s[2][3]), s[3][0]);
    mx = fmaxf(fmaxf(mx, s[3][1]), s[3][2]);
    mx = fmaxf(mx, s[3][3]);
    mx = fmaxf(mx, __shfl_xor(mx, 16));
    mx = fmaxf(mx, __shfl_xor(mx, 32));
    if (!__all(mx - m_run <= 44.36f)) {
      float mnew = fmaxf(m_run, mx);
      float alpha = exp2f((m_run - mnew) * CE);
      m_run = mnew;
      l_run *= alpha;
#pragma unroll
      for (int d = 0; d < 4; d++) o[d] *= alpha;
    }
    float mc = m_run * CE;
    float rs = 0.f;
#pragma unroll
    for (int n = 0; n < 4; n++)
#pragma unroll
      for (int r = 0; r < 4; r++) {
        float p = exp2f(s[n][r] * CE - mc);
        s[n][r] = p;
        rs += p;
      }
    l_run += rs;

    ushort* Pw = &Ps[w][0];
#pragma unroll
    for (int n = 0; n < 4; n++) {
      int col = (n * 16 + l4 * 4) ^ swz_rd;
      uint2 pk;
      pk.x = pkbf(s[n][0], s[n][1]);
      pk.y = pkbf(s[n][2], s[n][3]);
      *(uint2*)&Pw[l15 * 64 + col] = pk;
    }

    bf16x8 pa[2];
#pragma unroll
    for (int cc = 0; cc < 2; cc++)
      pa[cc] = *(const bf16x8*)&Pw[l15 * 64 + ((cc * 32 + l4 * 8) ^ swz_rd)];

    __builtin_amdgcn_s_setprio(1);
#pragma unroll
    for (int d = 0; d < 4; d++) {
      int dr = d * 16 + l15;
#pragma unroll
      for (int cc = 0; cc < 2; cc++) {
        bf16x8 av = *(const bf16x8*)&Vs[buf][dr * 64 + ((cc * 32 + l4 * 8) ^ swz_rd)];
        o[d] = __builtin_amdgcn_mfma_f32_16x16x32_bf16(av, pa[cc], o[d], 0, 0, 0);
      }
    }
    __builtin_amdgcn_s_setprio(0);

    __syncthreads();
    buf ^= 1;
  }

  float lv = l_run;
  lv += __shfl_xor(lv, 16);
  lv += __shfl_xor(lv, 32);
  float inv = 1.f / lv;
  size_t rowbase = ((size_t)(b * SS + q0 + l15)) * DDIM + h * DEPTH;
#pragma unroll
  for (int d = 0; d < 4; d++) {
    *(uint*)&ctx[rowbase + d * 16 + l4 * 4]     = pkbf(o[d][0] * inv, o[d][1] * inv);
    *(uint*)&ctx[rowbase + d * 16 + l4 * 4 + 2] = pkbf(o[d][2] * inv, o[d][3] * inv);
  }
}

extern "C" void kernel_launch(void* const* d_in, const int* in_sizes, int n_in,
                              void* d_out, int out_size, void* d_ws, size_t ws_size,
                              hipStream_t stream) {
  const float* query = (const float*)d_in[0];
  const float* key_  = (const float*)d_in[1];
  const float* value = (const float*)d_in[2];
  const float* Wq = (const float*)d_in[4];
  const float* Wk = (const float*)d_in[5];
  const float* Wv = (const float*)d_in[6];
  const float* Wo = (const float*)d_in[7];
  const float* bq = (const float*)d_in[8];
  const float* bk = (const float*)d_in[9];
  const float* bv = (const float*)d_in[10];
  const float* bo = (const float*)d_in[11];

  char* ws = (char*)d_ws;
  const size_t MB = 1u << 20;
  ushort* Wqt = (ushort*)(ws + 24 * MB);
  ushort* Wkt = (ushort*)(ws + 26 * MB);
  ushort* Wvt = (ushort*)(ws + 28 * MB);
  ushort* Wot = (ushort*)(ws + 30 * MB);
  ushort* Qh  = (ushort*)(ws + 32 * MB);   // [bh][2048][64]
  ushort* Kh  = (ushort*)(ws + 40 * MB);   // [bh][2048][64]
  ushort* Vtg = (ushort*)(ws + 48 * MB);   // [bh][64][2048]
  ushort* Cb  = (ushort*)(ws + 56 * MB);   // [4096][1024]

  wprep_kernel<<<4096, 256, 0, stream>>>(Wq, Wk, Wv, Wo, Wqt, Wkt, Wvt, Wot);

  qkv_gemm_kernel<<<768, 256, 0, stream>>>(
      query, key_, value, Wqt, Wkt, Wvt, bq, bk, bv, Qh, Kh, Vtg);

  attn_kernel<<<1024, 256, 0, stream>>>(Qh, Kh, Vtg, Cb);

  out_gemm_kernel<<<512, 256, 0, stream>>>(
      Cb, Wot, bo, (float*)d_out, MROWS, DDIM, DDIM);
}

// Round 13
// 115.783 us; speedup vs baseline: 1.3355x; 1.3355x over previous
//
#include <hip/hip_runtime.h>
#include <hip/hip_bf16.h>
#include <stdint.h>

#define BB 2
#define SS 2048
#define DDIM 1024
#define HH 16
#define DEPTH 64
#define MROWS (BB*SS)   // 4096

typedef short bf16x8 __attribute__((ext_vector_type(8)));
typedef float f32x4 __attribute__((ext_vector_type(4)));

__device__ inline ushort f2bf(float f) {
  union { float f; unsigned u; } v; v.f = f;
  unsigned r = v.u + 0x7fffu + ((v.u >> 16) & 1u);
  return (ushort)(r >> 16);
}

// HW packed f32x2 -> bf16x2 (RTNE), low = a, high = b  [m214 T12]
__device__ inline uint pkbf(float a, float b) {
  uint r;
  asm("v_cvt_pk_bf16_f32 %0, %1, %2" : "=v"(r) : "v"(a), "v"(b));
  return r;
}

__device__ inline void gload_lds16(const void* g, void* l) {
  __builtin_amdgcn_global_load_lds(
      (const __attribute__((address_space(1))) unsigned*)g,
      (__attribute__((address_space(3))) unsigned*)l,
      16, 0, 0);
}

// ---------------- weight transpose + convert: T[n][k] = W[k][n] ----------------
__global__ void wprep_kernel(const float* __restrict__ W0, const float* __restrict__ W1,
                             const float* __restrict__ W2, const float* __restrict__ W3,
                             ushort* __restrict__ T0, ushort* __restrict__ T1,
                             ushort* __restrict__ T2, ushort* __restrict__ T3) {
  __shared__ float tile[32][33];
  int z = blockIdx.x >> 10;
  int rr = blockIdx.x & 1023;
  const float* W = (z == 0) ? W0 : (z == 1) ? W1 : (z == 2) ? W2 : W3;
  ushort* T = (z == 0) ? T0 : (z == 1) ? T1 : (z == 2) ? T2 : T3;
  int tx = threadIdx.x & 31, ty = threadIdx.x >> 5;   // 32 x 8
  int n0 = (rr & 31) * 32, k0 = (rr >> 5) * 32;
#pragma unroll
  for (int i = 0; i < 4; i++)
    tile[ty + i * 8][tx] = W[(size_t)(k0 + ty + i * 8) * DDIM + n0 + tx];
  __syncthreads();
#pragma unroll
  for (int i = 0; i < 4; i++)
    T[(size_t)(n0 + ty + i * 8) * DDIM + k0 + tx] = f2bf(tile[tx][ty + i * 8]);
}

// ---------------- fused Q/K/V projection GEMM, BK=64, pipelined 2-phase ----------
// (r8-proven structure). A (fp32) reg-staged+cvt fused; B gload_lds dbuf.
__global__ __launch_bounds__(256, 3) void qkv_gemm_kernel(
    const float* __restrict__ Aq, const float* __restrict__ Ak, const float* __restrict__ Av,
    const ushort* __restrict__ Wqt, const ushort* __restrict__ Wkt, const ushort* __restrict__ Wvt,
    const float* __restrict__ bqp, const float* __restrict__ bkp, const float* __restrict__ bvp,
    ushort* __restrict__ Qh, ushort* __restrict__ Kh, ushort* __restrict__ Vtg) {
  const int id = blockIdx.x;
  const int xcd = id & 7;
  const int rest = id >> 3;          // 0..95
  const int xblk = rest & 7;         // n-block 0..7
  const int slot = rest >> 3;        // 0..11
  const int g = xcd * 12 + slot;     // 0..95
  const int yblk = g & 31;           // m-panel 0..31
  const int z = g >> 5;              // tensor 0..2

  const float*  Ap = (z == 0) ? Aq  : (z == 1) ? Ak  : Av;
  const ushort* Bt = (z == 0) ? Wqt : (z == 1) ? Wkt : Wvt;
  const float* bias = (z == 0) ? bqp : (z == 1) ? bkp : bvp;

  __shared__ __align__(16) ushort As[128 * 64];        // 16 KB
  __shared__ __align__(16) ushort Bs[2][128 * 64];     // 32 KB
  const int tid = threadIdx.x;
  const int w = tid >> 6, lane = tid & 63;
  const int m0 = yblk * 128, n0 = xblk * 128;
  const int wr = (w >> 1) * 64, wc = (w & 1) * 64;
  const int l4 = lane >> 4, l15 = lane & 15;
  const int row16 = tid >> 4;          // 0..15
  const int col4 = (tid & 15) * 4;     // fp32/bf16 col within 64
  const int srow8 = w * 8 + (lane >> 3);
  const int scol8 = (lane & 7) * 8;

  f32x4 zero = {0.f, 0.f, 0.f, 0.f};
  f32x4 acc[4][4];
#pragma unroll
  for (int i = 0; i < 4; i++)
#pragma unroll
    for (int j = 0; j < 4; j++) acc[i][j] = zero;

  // ---- prologue: tile 0 ----
  float4 areg[8];
#pragma unroll
  for (int j = 0; j < 8; ++j)
    areg[j] = *(const float4*)&Ap[(size_t)(m0 + j * 16 + row16) * DDIM + col4];
#pragma unroll
  for (int it = 0; it < 4; ++it)
    gload_lds16(Bt + (size_t)(n0 + it * 32 + srow8) * DDIM + scol8,
                &Bs[0][(it * 32 + w * 8) * 64]);
#pragma unroll
  for (int j = 0; j < 8; ++j) {
    uint2 pk;
    pk.x = pkbf(areg[j].x, areg[j].y);
    pk.y = pkbf(areg[j].z, areg[j].w);
    *(uint2*)&As[(j * 16 + row16) * 64 + col4] = pk;
  }
  __syncthreads();

  int buf = 0;
  for (int t = 0; t < 16; ++t) {
    if (t + 1 < 16) {
#pragma unroll
      for (int it = 0; it < 4; ++it)
        gload_lds16(Bt + (size_t)(n0 + it * 32 + srow8) * DDIM + (t + 1) * 64 + scol8,
                    &Bs[buf ^ 1][(it * 32 + w * 8) * 64]);
#pragma unroll
      for (int j = 0; j < 8; ++j)
        areg[j] = *(const float4*)&Ap[(size_t)(m0 + j * 16 + row16) * DDIM + (t + 1) * 64 + col4];
    }
#pragma unroll
    for (int kk = 0; kk < 2; ++kk) {
      bf16x8 af[4], bfr[4];
#pragma unroll
      for (int m = 0; m < 4; m++)
        af[m] = *(const bf16x8*)&As[(wr + m * 16 + l15) * 64 + kk * 32 + l4 * 8];
#pragma unroll
      for (int n = 0; n < 4; n++)
        bfr[n] = *(const bf16x8*)&Bs[buf][(wc + n * 16 + l15) * 64 + kk * 32 + l4 * 8];
#pragma unroll
      for (int m = 0; m < 4; m++)
#pragma unroll
        for (int n = 0; n < 4; n++)
          acc[m][n] = __builtin_amdgcn_mfma_f32_16x16x32_bf16(af[m], bfr[n], acc[m][n], 0, 0, 0);
    }
    __syncthreads();
    if (t + 1 < 16) {
#pragma unroll
      for (int j = 0; j < 8; ++j) {
        uint2 pk;
        pk.x = pkbf(areg[j].x, areg[j].y);
        pk.y = pkbf(areg[j].z, areg[j].w);
        *(uint2*)&As[(j * 16 + row16) * 64 + col4] = pk;
      }
    }
    __syncthreads();
    buf ^= 1;
  }

  if (z != 2) {
    ushort* outp = (z == 0) ? Qh : Kh;
    ushort* wtile = (w < 2) ? &As[w * 4096] : &Bs[0][(w - 2) * 4096];
    const int gcol0 = n0 + wc;
    const int hh = gcol0 >> 6;
    const int bb = m0 >> 11;
    const int s0g = (m0 + wr) & (SS - 1);
#pragma unroll
    for (int m = 0; m < 4; m++) {
#pragma unroll
      for (int n = 0; n < 4; n++) {
        int dloc = n * 16 + l15;
        float bv = bias[gcol0 + dloc];
#pragma unroll
        for (int r = 0; r < 4; r++) {
          int sloc = m * 16 + l4 * 4 + r;
          wtile[sloc * 64 + (dloc ^ ((sloc & 7) << 3))] = f2bf(acc[m][n][r] + bv);
        }
      }
    }
#pragma unroll
    for (int i = 0; i < 8; ++i) {
      int srow = i * 8 + (lane >> 3);
      int dch = (lane & 7) * 8;
      bf16x8 val = *(const bf16x8*)&wtile[srow * 64 + (dch ^ ((srow & 7) << 3))];
      *(bf16x8*)&outp[((size_t)(bb * HH + hh) * SS + s0g + srow) * DEPTH + dch] = val;
    }
  } else {
    ushort* wtile = (w < 2) ? &As[w * 2048] : &Bs[0][(w - 2) * 2048];
    const int gcol0 = n0 + wc;
    const int hh = gcol0 >> 6;
    const int bb = m0 >> 11;
    const int s0g = (m0 + wr) & (SS - 1);
#pragma unroll
    for (int p = 0; p < 2; ++p) {
#pragma unroll
      for (int nn = 0; nn < 2; ++nn) {
        int n = p * 2 + nn;
        int dloc = nn * 16 + l15;
        float bv = bias[gcol0 + p * 32 + dloc];
#pragma unroll
        for (int m = 0; m < 4; m++) {
#pragma unroll
          for (int rr = 0; rr < 4; rr += 2) {
            int sloc = m * 16 + l4 * 4 + rr;
            int gg = (sloc >> 3) ^ (dloc & 7);
            uint pk = pkbf(acc[m][n][rr] + bv, acc[m][n][rr + 1] + bv);
            *(uint*)&wtile[dloc * 64 + gg * 8 + (sloc & 7)] = pk;
          }
        }
      }
      __syncthreads();
#pragma unroll
      for (int i = 0; i < 4; ++i) {
        int dloc = (lane >> 3) + i * 8;
        int gg = (lane & 7) ^ (dloc & 7);
        bf16x8 val = *(const bf16x8*)&wtile[dloc * 64 + gg * 8];
        int dglob = p * 32 + dloc;
        size_t addr = ((size_t)(bb * HH + hh) * DEPTH + dglob) * SS + s0g + (lane & 7) * 8;
        *(bf16x8*)&Vtg[addr] = val;
      }
      __syncthreads();
    }
  }
}

// ---------------- output GEMM: 128x64 tile, BK=64, full dbuf, 1 barrier/iter -----
__global__ __launch_bounds__(256, 3) void out_gemm_kernel(
    const ushort* __restrict__ A, const ushort* __restrict__ Bt,
    const float* __restrict__ bias, float* __restrict__ out,
    int M, int N, int K) {
  __shared__ __align__(16) ushort As[2][128 * 64];   // 32 KB
  __shared__ __align__(16) ushort Bs[2][64 * 64];    // 16 KB
  const int id = blockIdx.x;
  const int xcd = id & 7;
  const int rest = id >> 3;          // 0..63
  const int xblk = rest & 15;        // n-block 0..15
  const int slot = rest >> 4;        // 0..3
  const int yblk = xcd * 4 + slot;   // m-panel 0..31

  const int tid = threadIdx.x;
  const int w = tid >> 6, lane = tid & 63;
  const int m0 = yblk * 128, n0 = xblk * 64;
  const int wr = (w >> 1) * 64, wc = (w & 1) * 32;
  const int l4 = lane >> 4, l15 = lane & 15;
  const int srow8 = w * 8 + (lane >> 3);
  const int scol8 = (lane & 7) * 8;

  f32x4 zero = {0.f, 0.f, 0.f, 0.f};
  f32x4 acc[4][2];
#pragma unroll
  for (int i = 0; i < 4; i++)
#pragma unroll
    for (int j = 0; j < 2; j++) acc[i][j] = zero;

#pragma unroll
  for (int it = 0; it < 4; ++it)
    gload_lds16(A + (size_t)(m0 + it * 32 + srow8) * K + scol8,
                &As[0][(it * 32 + w * 8) * 64]);
#pragma unroll
  for (int it = 0; it < 2; ++it)
    gload_lds16(Bt + (size_t)(n0 + it * 32 + srow8) * K + scol8,
                &Bs[0][(it * 32 + w * 8) * 64]);
  __syncthreads();

  int buf = 0;
  for (int t = 0; t < 16; ++t) {
    if (t + 1 < 16) {
#pragma unroll
      for (int it = 0; it < 4; ++it)
        gload_lds16(A + (size_t)(m0 + it * 32 + srow8) * K + (t + 1) * 64 + scol8,
                    &As[buf ^ 1][(it * 32 + w * 8) * 64]);
#pragma unroll
      for (int it = 0; it < 2; ++it)
        gload_lds16(Bt + (size_t)(n0 + it * 32 + srow8) * K + (t + 1) * 64 + scol8,
                    &Bs[buf ^ 1][(it * 32 + w * 8) * 64]);
    }
#pragma unroll
    for (int kk = 0; kk < 2; ++kk) {
      bf16x8 af[4], bfr[2];
#pragma unroll
      for (int m = 0; m < 4; m++)
        af[m] = *(const bf16x8*)&As[buf][(wr + m * 16 + l15) * 64 + kk * 32 + l4 * 8];
#pragma unroll
      for (int n = 0; n < 2; n++)
        bfr[n] = *(const bf16x8*)&Bs[buf][(wc + n * 16 + l15) * 64 + kk * 32 + l4 * 8];
#pragma unroll
      for (int m = 0; m < 4; m++)
#pragma unroll
        for (int n = 0; n < 2; n++)
          acc[m][n] = __builtin_amdgcn_mfma_f32_16x16x32_bf16(af[m], bfr[n], acc[m][n], 0, 0, 0);
    }
    __syncthreads();
    buf ^= 1;
  }

#pragma unroll
  for (int m = 0; m < 4; m++) {
#pragma unroll
    for (int n = 0; n < 2; n++) {
      int col = n0 + wc + n * 16 + l15;
      float bv = bias[col];
#pragma unroll
      for (int r = 0; r < 4; r++) {
        int row = m0 + wr + m * 16 + l4 * 4 + r;
        out[(size_t)row * N + col] = acc[m][n][r] + bv;
      }
    }
  }
}

// ---------------- causal flash attention: max3 + running ptrs (r11-proven) ------
__global__ __launch_bounds__(256, 4) void attn_kernel(
    const ushort* __restrict__ Qh, const ushort* __restrict__ Kh,
    const ushort* __restrict__ Vt, ushort* __restrict__ ctx) {
  __shared__ __align__(16) ushort Ks[2][64 * 64];   // [kv][d], XOR-swizzled
  __shared__ __align__(16) ushort Vs[2][64 * 64];   // [d][kv], XOR-swizzled
  __shared__ __align__(16) ushort Ps[4][16 * 64];   // per-wave P, XOR-swizzled
  const int tid = threadIdx.x;
  const int w = tid >> 6, lane = tid & 63;
  const int l4 = lane >> 4, l15 = lane & 15;
  const float CE = 0.18033688f;                     // 0.125 * log2(e)

  const int xcd = blockIdx.x & 7;
  const int local = blockIdx.x >> 3;                // 0..127
  const int bh = xcd * 4 + (local & 3);
  const int chunk = 31 - (local >> 2);
  const int b = bh >> 4, h = bh & 15;
  const size_t qkbase = (size_t)bh * SS * DEPTH;
  const size_t vbase  = (size_t)bh * DEPTH * SS;

  const int srow_w = w * 8 + (lane >> 3);
  const int colb_lin = (lane & 7) * 16;
  const int swz_rd = (l15 & 7) << 3;

  const int q0 = chunk * 64 + w * 16;
  const int nt = chunk + 1;

  const int krow0 = srow_w;
  const int kcol  = (colb_lin ^ ((krow0 & 7) << 4)) >> 1;
  const ushort* kp0 = Kh + qkbase + (size_t)krow0 * DEPTH + kcol;
  const ushort* kp1 = kp0 + 32 * DEPTH;
  const ushort* vp0 = Vt + vbase + (size_t)krow0 * SS + kcol;
  const ushort* vp1 = vp0 + 32 * SS;
  const int lds0 = w * 512;
  const int lds1 = 2048 + w * 512;

  bf16x8 aq[2];
#pragma unroll
  for (int cc = 0; cc < 2; cc++)
    aq[cc] = *(const bf16x8*)&Qh[qkbase + (size_t)(q0 + l15) * DEPTH + cc * 32 + l4 * 8];

  f32x4 zero = {0.f, 0.f, 0.f, 0.f};
  f32x4 o[4];
  float m_run = -__builtin_inff(), l_run = 0.f;
#pragma unroll
  for (int d = 0; d < 4; d++) o[d] = zero;

  int buf = 0;
  gload_lds16(kp0, &Ks[0][lds0]);
  gload_lds16(vp0, &Vs[0][lds0]);
  gload_lds16(kp1, &Ks[0][lds1]);
  gload_lds16(vp1, &Vs[0][lds1]);
  kp0 += 64 * DEPTH; kp1 += 64 * DEPTH; vp0 += 64; vp1 += 64;
  __syncthreads();

  for (int t = 0; t < nt; ++t) {
    if (t + 1 < nt) {
      gload_lds16(kp0, &Ks[buf ^ 1][lds0]);
      gload_lds16(vp0, &Vs[buf ^ 1][lds0]);
      gload_lds16(kp1, &Ks[buf ^ 1][lds1]);
      gload_lds16(vp1, &Vs[buf ^ 1][lds1]);
      kp0 += 64 * DEPTH; kp1 += 64 * DEPTH; vp0 += 64; vp1 += 64;
    }

    const int kv0 = t * 64;
    f32x4 s[4];
    __builtin_amdgcn_s_setprio(1);
#pragma unroll
    for (int n = 0; n < 4; n++) {
      f32x4 zacc = zero;
      int kr = n * 16 + l15;
#pragma unroll
      for (int cc = 0; cc < 2; cc++) {
        bf16x8 bk = *(const bf16x8*)&Ks[buf][kr * 64 + ((cc * 32 + l4 * 8) ^ swz_rd)];
        zacc = __builtin_amdgcn_mfma_f32_16x16x32_bf16(bk, aq[cc], zacc, 0, 0, 0);
      }
      s[n] = zacc;
    }
    __builtin_amdgcn_s_setprio(0);

    const int qg = q0 + l15;
    if (t == nt - 1) {
#pragma unroll
      for (int n = 0; n < 4; n++) {
        int kb = kv0 + n * 16 + l4 * 4;
#pragma unroll
        for (int r = 0; r < 4; r++)
          if (kb + r > qg) s[n][r] = -1e9f;
      }
    }

    float mx = fmaxf(fmaxf(s[0][0], s[0][1]), s[0][2]);
    mx = fmaxf(fmaxf(mx, s[0][3]), s[1][0]);
    mx = fmaxf(fmaxf(mx, s[1][1]), s[1][2]);
    mx = fmaxf(fmaxf(mx, s[1][3]), s[2][0]);
    mx = fmaxf(fmaxf(mx, s[2][1]), s[2][2]);
    mx = fmaxf(fmaxf(mx, s[2][3]), s[3][0]);
    mx = fmaxf(fmaxf(mx, s[3][1]), s[3][2]);
    mx = fmaxf(mx, s[3][3]);
    mx = fmaxf(mx, __shfl_xor(mx, 16));
    mx = fmaxf(mx, __shfl_xor(mx, 32));
    if (!__all(mx - m_run <= 44.36f)) {
      float mnew = fmaxf(m_run, mx);
      float alpha = exp2f((m_run - mnew) * CE);
      m_run = mnew;
      l_run *= alpha;
#pragma unroll
      for (int d = 0; d < 4; d++) o[d] *= alpha;
    }
    float mc = m_run * CE;
    float rs = 0.f;
#pragma unroll
    for (int n = 0; n < 4; n++)
#pragma unroll
      for (int r = 0; r < 4; r++) {
        float p = exp2f(s[n][r] * CE - mc);
        s[n][r] = p;
        rs += p;
      }
    l_run += rs;

    ushort* Pw = &Ps[w][0];
#pragma unroll
    for (int n = 0; n < 4; n++) {
      int col = (n * 16 + l4 * 4) ^ swz_rd;
      uint2 pk;
      pk.x = pkbf(s[n][0], s[n][1]);
      pk.y = pkbf(s[n][2], s[n][3]);
      *(uint2*)&Pw[l15 * 64 + col] = pk;
    }

    bf16x8 pa[2];
#pragma unroll
    for (int cc = 0; cc < 2; cc++)
      pa[cc] = *(const bf16x8*)&Pw[l15 * 64 + ((cc * 32 + l4 * 8) ^ swz_rd)];

    __builtin_amdgcn_s_setprio(1);
#pragma unroll
    for (int d = 0; d < 4; d++) {
      int dr = d * 16 + l15;
#pragma unroll
      for (int cc = 0; cc < 2; cc++) {
        bf16x8 av = *(const bf16x8*)&Vs[buf][dr * 64 + ((cc * 32 + l4 * 8) ^ swz_rd)];
        o[d] = __builtin_amdgcn_mfma_f32_16x16x32_bf16(av, pa[cc], o[d], 0, 0, 0);
      }
    }
    __builtin_amdgcn_s_setprio(0);

    __syncthreads();
    buf ^= 1;
  }

  float lv = l_run;
  lv += __shfl_xor(lv, 16);
  lv += __shfl_xor(lv, 32);
  float inv = 1.f / lv;
  size_t rowbase = ((size_t)(b * SS + q0 + l15)) * DDIM + h * DEPTH;
#pragma unroll
  for (int d = 0; d < 4; d++) {
    *(uint*)&ctx[rowbase + d * 16 + l4 * 4]     = pkbf(o[d][0] * inv, o[d][1] * inv);
    *(uint*)&ctx[rowbase + d * 16 + l4 * 4 + 2] = pkbf(o[d][2] * inv, o[d][3] * inv);
  }
}

extern "C" void kernel_launch(void* const* d_in, const int* in_sizes, int n_in,
                              void* d_out, int out_size, void* d_ws, size_t ws_size,
                              hipStream_t stream) {
  const float* query = (const float*)d_in[0];
  const float* key_  = (const float*)d_in[1];
  const float* value = (const float*)d_in[2];
  const float* Wq = (const float*)d_in[4];
  const float* Wk = (const float*)d_in[5];
  const float* Wv = (const float*)d_in[6];
  const float* Wo = (const float*)d_in[7];
  const float* bq = (const float*)d_in[8];
  const float* bk = (const float*)d_in[9];
  const float* bv = (const float*)d_in[10];
  const float* bo = (const float*)d_in[11];

  char* ws = (char*)d_ws;
  const size_t MB = 1u << 20;
  ushort* Wqt = (ushort*)(ws + 24 * MB);
  ushort* Wkt = (ushort*)(ws + 26 * MB);
  ushort* Wvt = (ushort*)(ws + 28 * MB);
  ushort* Wot = (ushort*)(ws + 30 * MB);
  ushort* Qh  = (ushort*)(ws + 32 * MB);   // [bh][2048][64]
  ushort* Kh  = (ushort*)(ws + 40 * MB);   // [bh][2048][64]
  ushort* Vtg = (ushort*)(ws + 48 * MB);   // [bh][64][2048]
  ushort* Cb  = (ushort*)(ws + 56 * MB);   // [4096][1024]

  wprep_kernel<<<4096, 256, 0, stream>>>(Wq, Wk, Wv, Wo, Wqt, Wkt, Wvt, Wot);

  qkv_gemm_kernel<<<768, 256, 0, stream>>>(
      query, key_, value, Wqt, Wkt, Wvt, bq, bk, bv, Qh, Kh, Vtg);

  attn_kernel<<<1024, 256, 0, stream>>>(Qh, Kh, Vtg, Cb);

  out_gemm_kernel<<<512, 256, 0, stream>>>(
      Cb, Wot, bo, (float*)d_out, MROWS, DDIM, DDIM);
}

// Round 14
// 107.885 us; speedup vs baseline: 1.4333x; 1.0732x over previous
//
#include <hip/hip_runtime.h>
#include <hip/hip_bf16.h>
#include <stdint.h>

#define BB 2
#define SS 2048
#define DDIM 1024
#define HH 16
#define DEPTH 64
#define MROWS (BB*SS)   // 4096

typedef short bf16x8 __attribute__((ext_vector_type(8)));
typedef float f32x4 __attribute__((ext_vector_type(4)));

__device__ inline ushort f2bf(float f) {
  union { float f; unsigned u; } v; v.f = f;
  unsigned r = v.u + 0x7fffu + ((v.u >> 16) & 1u);
  return (ushort)(r >> 16);
}

// HW packed f32x2 -> bf16x2 (RTNE), low = a, high = b  [m214 T12]
__device__ inline uint pkbf(float a, float b) {
  uint r;
  asm("v_cvt_pk_bf16_f32 %0, %1, %2" : "=v"(r) : "v"(a), "v"(b));
  return r;
}

__device__ inline void gload_lds16(const void* g, void* l) {
  __builtin_amdgcn_global_load_lds(
      (const __attribute__((address_space(1))) unsigned*)g,
      (__attribute__((address_space(3))) unsigned*)l,
      16, 0, 0);
}

// ---------------- weight transpose + convert: T[n][k] = W[k][n] ----------------
__global__ void wprep_kernel(const float* __restrict__ W0, const float* __restrict__ W1,
                             const float* __restrict__ W2, const float* __restrict__ W3,
                             ushort* __restrict__ T0, ushort* __restrict__ T1,
                             ushort* __restrict__ T2, ushort* __restrict__ T3) {
  __shared__ float tile[32][33];
  int z = blockIdx.x >> 10;
  int rr = blockIdx.x & 1023;
  const float* W = (z == 0) ? W0 : (z == 1) ? W1 : (z == 2) ? W2 : W3;
  ushort* T = (z == 0) ? T0 : (z == 1) ? T1 : (z == 2) ? T2 : T3;
  int tx = threadIdx.x & 31, ty = threadIdx.x >> 5;   // 32 x 8
  int n0 = (rr & 31) * 32, k0 = (rr >> 5) * 32;
#pragma unroll
  for (int i = 0; i < 4; i++)
    tile[ty + i * 8][tx] = W[(size_t)(k0 + ty + i * 8) * DDIM + n0 + tx];
  __syncthreads();
#pragma unroll
  for (int i = 0; i < 4; i++)
    T[(size_t)(n0 + ty + i * 8) * DDIM + k0 + tx] = f2bf(tile[tx][ty + i * 8]);
}

// ---------------- fused Q/K/V projection GEMM, BK=64, r8 structure + T2 swizzle --
// LDS element (row, c) holds global col (c ^ ((row&7)<<3)).
// A side: swizzle applied at cvt ds_write; B side: pre-swizzled per-lane global
// source col with linear gload_lds dest (m173 / rule #21). Frag reads XOR.
__global__ __launch_bounds__(256, 3) void qkv_gemm_kernel(
    const float* __restrict__ Aq, const float* __restrict__ Ak, const float* __restrict__ Av,
    const ushort* __restrict__ Wqt, const ushort* __restrict__ Wkt, const ushort* __restrict__ Wvt,
    const float* __restrict__ bqp, const float* __restrict__ bkp, const float* __restrict__ bvp,
    ushort* __restrict__ Qh, ushort* __restrict__ Kh, ushort* __restrict__ Vtg) {
  const int id = blockIdx.x;
  const int xcd = id & 7;
  const int rest = id >> 3;          // 0..95
  const int xblk = rest & 7;         // n-block 0..7
  const int slot = rest >> 3;        // 0..11
  const int g = xcd * 12 + slot;     // 0..95
  const int yblk = g & 31;           // m-panel 0..31
  const int z = g >> 5;              // tensor 0..2

  const float*  Ap = (z == 0) ? Aq  : (z == 1) ? Ak  : Av;
  const ushort* Bt = (z == 0) ? Wqt : (z == 1) ? Wkt : Wvt;
  const float* bias = (z == 0) ? bqp : (z == 1) ? bkp : bvp;

  __shared__ __align__(16) ushort As[128 * 64];        // 16 KB
  __shared__ __align__(16) ushort Bs[2][128 * 64];     // 32 KB
  const int tid = threadIdx.x;
  const int w = tid >> 6, lane = tid & 63;
  const int m0 = yblk * 128, n0 = xblk * 128;
  const int wr = (w >> 1) * 64, wc = (w & 1) * 64;
  const int l4 = lane >> 4, l15 = lane & 15;
  const int row16 = tid >> 4;          // 0..15
  const int col4 = (tid & 15) * 4;     // fp32/bf16 col within 64
  const int acolw = col4 ^ ((row16 & 7) << 3);            // swizzled A-write col
  const int srow8 = w * 8 + (lane >> 3);
  const int bcolg = (((lane & 7) ^ (lane >> 3)) << 3);    // pre-swizzled B source col
  const int fswz = (l15 & 7) << 3;                        // frag-read XOR

  f32x4 zero = {0.f, 0.f, 0.f, 0.f};
  f32x4 acc[4][4];
#pragma unroll
  for (int i = 0; i < 4; i++)
#pragma unroll
    for (int j = 0; j < 4; j++) acc[i][j] = zero;

  // ---- prologue: tile 0 ----
  float4 areg[8];
#pragma unroll
  for (int j = 0; j < 8; ++j)
    areg[j] = *(const float4*)&Ap[(size_t)(m0 + j * 16 + row16) * DDIM + col4];
#pragma unroll
  for (int it = 0; it < 4; ++it)
    gload_lds16(Bt + (size_t)(n0 + it * 32 + srow8) * DDIM + bcolg,
                &Bs[0][(it * 32 + w * 8) * 64]);
#pragma unroll
  for (int j = 0; j < 8; ++j) {
    uint2 pk;
    pk.x = pkbf(areg[j].x, areg[j].y);
    pk.y = pkbf(areg[j].z, areg[j].w);
    *(uint2*)&As[(j * 16 + row16) * 64 + acolw] = pk;
  }
  __syncthreads();

  int buf = 0;
  for (int t = 0; t < 16; ++t) {
    if (t + 1 < 16) {
#pragma unroll
      for (int it = 0; it < 4; ++it)
        gload_lds16(Bt + (size_t)(n0 + it * 32 + srow8) * DDIM + (t + 1) * 64 + bcolg,
                    &Bs[buf ^ 1][(it * 32 + w * 8) * 64]);
#pragma unroll
      for (int j = 0; j < 8; ++j)
        areg[j] = *(const float4*)&Ap[(size_t)(m0 + j * 16 + row16) * DDIM + (t + 1) * 64 + col4];
    }
#pragma unroll
    for (int kk = 0; kk < 2; ++kk) {
      bf16x8 af[4], bfr[4];
#pragma unroll
      for (int m = 0; m < 4; m++)
        af[m] = *(const bf16x8*)&As[(wr + m * 16 + l15) * 64 + ((kk * 32 + l4 * 8) ^ fswz)];
#pragma unroll
      for (int n = 0; n < 4; n++)
        bfr[n] = *(const bf16x8*)&Bs[buf][(wc + n * 16 + l15) * 64 + ((kk * 32 + l4 * 8) ^ fswz)];
#pragma unroll
      for (int m = 0; m < 4; m++)
#pragma unroll
        for (int n = 0; n < 4; n++)
          acc[m][n] = __builtin_amdgcn_mfma_f32_16x16x32_bf16(af[m], bfr[n], acc[m][n], 0, 0, 0);
    }
    __syncthreads();
    if (t + 1 < 16) {
#pragma unroll
      for (int j = 0; j < 8; ++j) {
        uint2 pk;
        pk.x = pkbf(areg[j].x, areg[j].y);
        pk.y = pkbf(areg[j].z, areg[j].w);
        *(uint2*)&As[(j * 16 + row16) * 64 + acolw] = pk;
      }
    }
    __syncthreads();
    buf ^= 1;
  }

  if (z != 2) {
    ushort* outp = (z == 0) ? Qh : Kh;
    ushort* wtile = (w < 2) ? &As[w * 4096] : &Bs[0][(w - 2) * 4096];
    const int gcol0 = n0 + wc;
    const int hh = gcol0 >> 6;
    const int bb = m0 >> 11;
    const int s0g = (m0 + wr) & (SS - 1);
#pragma unroll
    for (int m = 0; m < 4; m++) {
#pragma unroll
      for (int n = 0; n < 4; n++) {
        int dloc = n * 16 + l15;
        float bv = bias[gcol0 + dloc];
#pragma unroll
        for (int r = 0; r < 4; r++) {
          int sloc = m * 16 + l4 * 4 + r;
          wtile[sloc * 64 + (dloc ^ ((sloc & 7) << 3))] = f2bf(acc[m][n][r] + bv);
        }
      }
    }
#pragma unroll
    for (int i = 0; i < 8; ++i) {
      int srow = i * 8 + (lane >> 3);
      int dch = (lane & 7) * 8;
      bf16x8 val = *(const bf16x8*)&wtile[srow * 64 + (dch ^ ((srow & 7) << 3))];
      *(bf16x8*)&outp[((size_t)(bb * HH + hh) * SS + s0g + srow) * DEPTH + dch] = val;
    }
  } else {
    ushort* wtile = (w < 2) ? &As[w * 2048] : &Bs[0][(w - 2) * 2048];
    const int gcol0 = n0 + wc;
    const int hh = gcol0 >> 6;
    const int bb = m0 >> 11;
    const int s0g = (m0 + wr) & (SS - 1);
#pragma unroll
    for (int p = 0; p < 2; ++p) {
#pragma unroll
      for (int nn = 0; nn < 2; ++nn) {
        int n = p * 2 + nn;
        int dloc = nn * 16 + l15;
        float bv = bias[gcol0 + p * 32 + dloc];
#pragma unroll
        for (int m = 0; m < 4; m++) {
#pragma unroll
          for (int rr = 0; rr < 4; rr += 2) {
            int sloc = m * 16 + l4 * 4 + rr;
            int gg = (sloc >> 3) ^ (dloc & 7);
            uint pk = pkbf(acc[m][n][rr] + bv, acc[m][n][rr + 1] + bv);
            *(uint*)&wtile[dloc * 64 + gg * 8 + (sloc & 7)] = pk;
          }
        }
      }
      __syncthreads();
#pragma unroll
      for (int i = 0; i < 4; ++i) {
        int dloc = (lane >> 3) + i * 8;
        int gg = (lane & 7) ^ (dloc & 7);
        bf16x8 val = *(const bf16x8*)&wtile[dloc * 64 + gg * 8];
        int dglob = p * 32 + dloc;
        size_t addr = ((size_t)(bb * HH + hh) * DEPTH + dglob) * SS + s0g + (lane & 7) * 8;
        *(bf16x8*)&Vtg[addr] = val;
      }
      __syncthreads();
    }
  }
}

// ---------------- output GEMM: 128x64, BK=64, full dbuf + T2 swizzle -------------
__global__ __launch_bounds__(256, 3) void out_gemm_kernel(
    const ushort* __restrict__ A, const ushort* __restrict__ Bt,
    const float* __restrict__ bias, float* __restrict__ out,
    int M, int N, int K) {
  __shared__ __align__(16) ushort As[2][128 * 64];   // 32 KB
  __shared__ __align__(16) ushort Bs[2][64 * 64];    // 16 KB
  const int id = blockIdx.x;
  const int xcd = id & 7;
  const int rest = id >> 3;          // 0..63
  const int xblk = rest & 15;        // n-block 0..15
  const int slot = rest >> 4;        // 0..3
  const int yblk = xcd * 4 + slot;   // m-panel 0..31

  const int tid = threadIdx.x;
  const int w = tid >> 6, lane = tid & 63;
  const int m0 = yblk * 128, n0 = xblk * 64;
  const int wr = (w >> 1) * 64, wc = (w & 1) * 32;
  const int l4 = lane >> 4, l15 = lane & 15;
  const int srow8 = w * 8 + (lane >> 3);
  const int scolg = (((lane & 7) ^ (lane >> 3)) << 3);  // pre-swizzled source col
  const int fswz = (l15 & 7) << 3;

  f32x4 zero = {0.f, 0.f, 0.f, 0.f};
  f32x4 acc[4][2];
#pragma unroll
  for (int i = 0; i < 4; i++)
#pragma unroll
    for (int j = 0; j < 2; j++) acc[i][j] = zero;

#pragma unroll
  for (int it = 0; it < 4; ++it)
    gload_lds16(A + (size_t)(m0 + it * 32 + srow8) * K + scolg,
                &As[0][(it * 32 + w * 8) * 64]);
#pragma unroll
  for (int it = 0; it < 2; ++it)
    gload_lds16(Bt + (size_t)(n0 + it * 32 + srow8) * K + scolg,
                &Bs[0][(it * 32 + w * 8) * 64]);
  __syncthreads();

  int buf = 0;
  for (int t = 0; t < 16; ++t) {
    if (t + 1 < 16) {
#pragma unroll
      for (int it = 0; it < 4; ++it)
        gload_lds16(A + (size_t)(m0 + it * 32 + srow8) * K + (t + 1) * 64 + scolg,
                    &As[buf ^ 1][(it * 32 + w * 8) * 64]);
#pragma unroll
      for (int it = 0; it < 2; ++it)
        gload_lds16(Bt + (size_t)(n0 + it * 32 + srow8) * K + (t + 1) * 64 + scolg,
                    &Bs[buf ^ 1][(it * 32 + w * 8) * 64]);
    }
#pragma unroll
    for (int kk = 0; kk < 2; ++kk) {
      bf16x8 af[4], bfr[2];
#pragma unroll
      for (int m = 0; m < 4; m++)
        af[m] = *(const bf16x8*)&As[buf][(wr + m * 16 + l15) * 64 + ((kk * 32 + l4 * 8) ^ fswz)];
#pragma unroll
      for (int n = 0; n < 2; n++)
        bfr[n] = *(const bf16x8*)&Bs[buf][(wc + n * 16 + l15) * 64 + ((kk * 32 + l4 * 8) ^ fswz)];
#pragma unroll
      for (int m = 0; m < 4; m++)
#pragma unroll
        for (int n = 0; n < 2; n++)
          acc[m][n] = __builtin_amdgcn_mfma_f32_16x16x32_bf16(af[m], bfr[n], acc[m][n], 0, 0, 0);
    }
    __syncthreads();
    buf ^= 1;
  }

#pragma unroll
  for (int m = 0; m < 4; m++) {
#pragma unroll
    for (int n = 0; n < 2; n++) {
      int col = n0 + wc + n * 16 + l15;
      float bv = bias[col];
#pragma unroll
      for (int r = 0; r < 4; r++) {
        int row = m0 + wr + m * 16 + l4 * 4 + r;
        out[(size_t)row * N + col] = acc[m][n][r] + bv;
      }
    }
  }
}

// ---------------- causal flash attention: max3 + running ptrs (r11-proven) ------
__global__ __launch_bounds__(256, 4) void attn_kernel(
    const ushort* __restrict__ Qh, const ushort* __restrict__ Kh,
    const ushort* __restrict__ Vt, ushort* __restrict__ ctx) {
  __shared__ __align__(16) ushort Ks[2][64 * 64];   // [kv][d], XOR-swizzled
  __shared__ __align__(16) ushort Vs[2][64 * 64];   // [d][kv], XOR-swizzled
  __shared__ __align__(16) ushort Ps[4][16 * 64];   // per-wave P, XOR-swizzled
  const int tid = threadIdx.x;
  const int w = tid >> 6, lane = tid & 63;
  const int l4 = lane >> 4, l15 = lane & 15;
  const float CE = 0.18033688f;                     // 0.125 * log2(e)

  const int xcd = blockIdx.x & 7;
  const int local = blockIdx.x >> 3;                // 0..127
  const int bh = xcd * 4 + (local & 3);
  const int chunk = 31 - (local >> 2);
  const int b = bh >> 4, h = bh & 15;
  const size_t qkbase = (size_t)bh * SS * DEPTH;
  const size_t vbase  = (size_t)bh * DEPTH * SS;

  const int srow_w = w * 8 + (lane >> 3);
  const int colb_lin = (lane & 7) * 16;
  const int swz_rd = (l15 & 7) << 3;

  const int q0 = chunk * 64 + w * 16;
  const int nt = chunk + 1;

  const int krow0 = srow_w;
  const int kcol  = (colb_lin ^ ((krow0 & 7) << 4)) >> 1;
  const ushort* kp0 = Kh + qkbase + (size_t)krow0 * DEPTH + kcol;
  const ushort* kp1 = kp0 + 32 * DEPTH;
  const ushort* vp0 = Vt + vbase + (size_t)krow0 * SS + kcol;
  const ushort* vp1 = vp0 + 32 * SS;
  const int lds0 = w * 512;
  const int lds1 = 2048 + w * 512;

  bf16x8 aq[2];
#pragma unroll
  for (int cc = 0; cc < 2; cc++)
    aq[cc] = *(const bf16x8*)&Qh[qkbase + (size_t)(q0 + l15) * DEPTH + cc * 32 + l4 * 8];

  f32x4 zero = {0.f, 0.f, 0.f, 0.f};
  f32x4 o[4];
  float m_run = -__builtin_inff(), l_run = 0.f;
#pragma unroll
  for (int d = 0; d < 4; d++) o[d] = zero;

  int buf = 0;
  gload_lds16(kp0, &Ks[0][lds0]);
  gload_lds16(vp0, &Vs[0][lds0]);
  gload_lds16(kp1, &Ks[0][lds1]);
  gload_lds16(vp1, &Vs[0][lds1]);
  kp0 += 64 * DEPTH; kp1 += 64 * DEPTH; vp0 += 64; vp1 += 64;
  __syncthreads();

  for (int t = 0; t < nt; ++t) {
    if (t + 1 < nt) {
      gload_lds16(kp0, &Ks[buf ^ 1][lds0]);
      gload_lds16(vp0, &Vs[buf ^ 1][lds0]);
      gload_lds16(kp1, &Ks[buf ^ 1][lds1]);
      gload_lds16(vp1, &Vs[buf ^ 1][lds1]);
      kp0 += 64 * DEPTH; kp1 += 64 * DEPTH; vp0 += 64; vp1 += 64;
    }

    const int kv0 = t * 64;
    f32x4 s[4];
    __builtin_amdgcn_s_setprio(1);
#pragma unroll
    for (int n = 0; n < 4; n++) {
      f32x4 zacc = zero;
      int kr = n * 16 + l15;
#pragma unroll
      for (int cc = 0; cc < 2; cc++) {
        bf16x8 bk = *(const bf16x8*)&Ks[buf][kr * 64 + ((cc * 32 + l4 * 8) ^ swz_rd)];
        zacc = __builtin_amdgcn_mfma_f32_16x16x32_bf16(bk, aq[cc], zacc, 0, 0, 0);
      }
      s[n] = zacc;
    }
    __builtin_amdgcn_s_setprio(0);

    const int qg = q0 + l15;
    if (t == nt - 1) {
#pragma unroll
      for (int n = 0; n < 4; n++) {
        int kb = kv0 + n * 16 + l4 * 4;
#pragma unroll
        for (int r = 0; r < 4; r++)
          if (kb + r > qg) s[n][r] = -1e9f;
      }
    }

    float mx = fmaxf(fmaxf(s[0][0], s[0][1]), s[0][2]);
    mx = fmaxf(fmaxf(mx, s[0][3]), s[1][0]);
    mx = fmaxf(fmaxf(mx, s[1][1]), s[1][2]);
    mx = fmaxf(fmaxf(mx, s[1][3]), s[2][0]);
    mx = fmaxf(fmaxf(mx, s[2][1]), s[2][2]);
    mx = fmaxf(fmaxf(mx, s[2][3]), s[3][0]);
    mx = fmaxf(fmaxf(mx, s[3][1]), s[3][2]);
    mx = fmaxf(mx, s[3][3]);
    mx = fmaxf(mx, __shfl_xor(mx, 16));
    mx = fmaxf(mx, __shfl_xor(mx, 32));
    if (!__all(mx - m_run <= 44.36f)) {
      float mnew = fmaxf(m_run, mx);
      float alpha = exp2f((m_run - mnew) * CE);
      m_run = mnew;
      l_run *= alpha;
#pragma unroll
      for (int d = 0; d < 4; d++) o[d] *= alpha;
    }
    float mc = m_run * CE;
    float rs = 0.f;
#pragma unroll
    for (int n = 0; n < 4; n++)
#pragma unroll
      for (int r = 0; r < 4; r++) {
        float p = exp2f(s[n][r] * CE - mc);
        s[n][r] = p;
        rs += p;
      }
    l_run += rs;

    ushort* Pw = &Ps[w][0];
#pragma unroll
    for (int n = 0; n < 4; n++) {
      int col = (n * 16 + l4 * 4) ^ swz_rd;
      uint2 pk;
      pk.x = pkbf(s[n][0], s[n][1]);
      pk.y = pkbf(s[n][2], s[n][3]);
      *(uint2*)&Pw[l15 * 64 + col] = pk;
    }

    bf16x8 pa[2];
#pragma unroll
    for (int cc = 0; cc < 2; cc++)
      pa[cc] = *(const bf16x8*)&Pw[l15 * 64 + ((cc * 32 + l4 * 8) ^ swz_rd)];

    __builtin_amdgcn_s_setprio(1);
#pragma unroll
    for (int d = 0; d < 4; d++) {
      int dr = d * 16 + l15;
#pragma unroll
      for (int cc = 0; cc < 2; cc++) {
        bf16x8 av = *(const bf16x8*)&Vs[buf][dr * 64 + ((cc * 32 + l4 * 8) ^ swz_rd)];
        o[d] = __builtin_amdgcn_mfma_f32_16x16x32_bf16(av, pa[cc], o[d], 0, 0, 0);
      }
    }
    __builtin_amdgcn_s_setprio(0);

    __syncthreads();
    buf ^= 1;
  }

  float lv = l_run;
  lv += __shfl_xor(lv, 16);
  lv += __shfl_xor(lv, 32);
  float inv = 1.f / lv;
  size_t rowbase = ((size_t)(b * SS + q0 + l15)) * DDIM + h * DEPTH;
#pragma unroll
  for (int d = 0; d < 4; d++) {
    *(uint*)&ctx[rowbase + d * 16 + l4 * 4]     = pkbf(o[d][0] * inv, o[d][1] * inv);
    *(uint*)&ctx[rowbase + d * 16 + l4 * 4 + 2] = pkbf(o[d][2] * inv, o[d][3] * inv);
  }
}

extern "C" void kernel_launch(void* const* d_in, const int* in_sizes, int n_in,
                              void* d_out, int out_size, void* d_ws, size_t ws_size,
                              hipStream_t stream) {
  const float* query = (const float*)d_in[0];
  const float* key_  = (const float*)d_in[1];
  const float* value = (const float*)d_in[2];
  const float* Wq = (const float*)d_in[4];
  const float* Wk = (const float*)d_in[5];
  const float* Wv = (const float*)d_in[6];
  const float* Wo = (const float*)d_in[7];
  const float* bq = (const float*)d_in[8];
  const float* bk = (const float*)d_in[9];
  const float* bv = (const float*)d_in[10];
  const float* bo = (const float*)d_in[11];

  char* ws = (char*)d_ws;
  const size_t MB = 1u << 20;
  ushort* Wqt = (ushort*)(ws + 24 * MB);
  ushort* Wkt = (ushort*)(ws + 26 * MB);
  ushort* Wvt = (ushort*)(ws + 28 * MB);
  ushort* Wot = (ushort*)(ws + 30 * MB);
  ushort* Qh  = (ushort*)(ws + 32 * MB);   // [bh][2048][64]
  ushort* Kh  = (ushort*)(ws + 40 * MB);   // [bh][2048][64]
  ushort* Vtg = (ushort*)(ws + 48 * MB);   // [bh][64][2048]
  ushort* Cb  = (ushort*)(ws + 56 * MB);   // [4096][1024]

  wprep_kernel<<<4096, 256, 0, stream>>>(Wq, Wk, Wv, Wo, Wqt, Wkt, Wvt, Wot);

  qkv_gemm_kernel<<<768, 256, 0, stream>>>(
      query, key_, value, Wqt, Wkt, Wvt, bq, bk, bv, Qh, Kh, Vtg);

  attn_kernel<<<1024, 256, 0, stream>>>(Qh, Kh, Vtg, Cb);

  out_gemm_kernel<<<512, 256, 0, stream>>>(
      Cb, Wot, bo, (float*)d_out, MROWS, DDIM, DDIM);
}